// Round 9
// baseline (154.608 us; speedup 1.0000x reference)
//
#include <hip/hip_runtime.h>
#include <math.h>

#define NLVL 8
#define PR1 2654435761u
#define PR2 805459861u

typedef __fp16    h2v   __attribute__((ext_vector_type(2)));   // cvt_pkrtz return type
typedef _Float16  half4 __attribute__((ext_vector_type(4)));   // 16x16x16 MFMA A/B operand
typedef float     floatx4 __attribute__((ext_vector_type(4)));

// Legacy K=16 MFMA builtins use the no-underscore dtype suffix on gfx950.
#define MFMA16(a,b,c) __builtin_amdgcn_mfma_f32_16x16x16f16(a,b,c,0,0,0)

union UH2 { unsigned u; h2v h; };

struct Res8 { float r[NLVL]; };

__device__ __forceinline__ unsigned pk2(float a, float b) {
    UH2 c; c.h = __builtin_amdgcn_cvt_pkrtz(a, b); return c.u;
}
__device__ __forceinline__ unsigned pkrelu(float a, float b) {
    UH2 c; c.h = __builtin_amdgcn_cvt_pkrtz(a, b);
    h2v z = {(__fp16)0.f, (__fp16)0.f};
    c.h = __builtin_elementwise_max(c.h, z);
    return c.u;
}
__device__ __forceinline__ half4 as_h4(uint2 u) {
    union { uint2 u; half4 h; } c; c.u = u; return c.h;
}
__device__ __forceinline__ h2v lerp2(h2v a, h2v b, h2v t) {
    return a + t * (b - a);
}

// Fused NGP, register-resident MLP chain (C/D frag of 16x16x16f16 == B frag of
// the next K=16 chunk -> inter-layer transpose is 2x cvt_pkrtz, zero LDS).
// amdgpu_waves_per_eu(4,4): LDS (52KB -> 2 blocks/CU) caps occupancy at
// 4 waves/EU anyway; without the pin the allocator targeted the 8-waves/EU
// bucket (64 VGPRs) and spilled ~31MB/launch to scratch (r8: WRITE_SIZE
// 31.5MB vs 8.2MB of output). Pin -> 128-VGPR budget, no spills.
__global__ __launch_bounds__(512) __attribute__((amdgpu_waves_per_eu(4, 4)))
void ngp_mfma_kernel(const float* __restrict__ x,
                     const float* __restrict__ table,
                     const float* __restrict__ w1,
                     const float* __restrict__ w2,
                     const float* __restrict__ r1,
                     const float* __restrict__ r2,
                     const float* __restrict__ r3,
                     float* __restrict__ out,
                     int N, int iters, Res8 res)
{
    __shared__ unsigned tab[NLVL * 1024];   // 32 KB packed f16x2
    __shared__ unsigned hstg[8][640];       // 20 KB: 64 pts x 10 dw (stride-10 pad)

    const int tid  = threadIdx.x;
    const int lane = tid & 63, wv = tid >> 6;
    const int m16  = lane & 15, q = lane >> 4;

    {   // stage table: 8192 float2 -> 8192 packed dwords (16/thread @ 512 thr)
        const float2* src = (const float2*)table;
        #pragma unroll
        for (int k = 0; k < 16; ++k) {
            int i = tid + 512 * k;
            float2 v = src[i];
            tab[i] = pk2(v.x, v.y);
        }
    }

    // Preload weight A-frags (W^T) for 16x16x16: A[m=m16][k=q*4+j]. 56 VGPRs.
    half4 A1[4], A2[4], A3[4], A4[4][4];
    #pragma unroll
    for (int mo = 0; mo < 4; ++mo)
        #pragma unroll
        for (int j = 0; j < 4; ++j) {
            int k = q * 4 + j;
            A1[mo][j] = (_Float16)w1[k * 64 + mo * 16 + m16];
            A3[mo][j] = (_Float16)r1[k * 64 + mo * 16 + m16];
            A2[mo][j] = (_Float16)w2[(mo * 16 + k) * 16 + m16];   // mo = K-chunk here
            #pragma unroll
            for (int kc = 0; kc < 4; ++kc)
                A4[kc][mo][j] = (_Float16)r2[(kc * 16 + k) * 64 + mo * 16 + m16];
        }
    float r3v[16];
    #pragma unroll
    for (int mo = 0; mo < 4; ++mo)
        #pragma unroll
        for (int r = 0; r < 4; ++r)
            r3v[mo * 4 + r] = r3[mo * 16 + q * 4 + r];

    __syncthreads();                        // table visible; only barrier in kernel

    unsigned* hs = hstg[wv];
    const char* tabb = (const char*)tab;
    const floatx4 cz = {0.f, 0.f, 0.f, 0.f};

    #pragma unroll 1
    for (int it = 0; it < iters; ++it) {
        const int pbase = (it * (int)gridDim.x + (int)blockIdx.x) * 512;
        int p = pbase + tid;                 // grid*threads*iters == N exactly

        float px = x[3 * p + 0] + 0.5f;
        float py = x[3 * p + 1] + 0.5f;
        float pz = x[3 * p + 2] + 0.5f;

        // ---- encode: 8 levels, 7-lerp trilinear tree on packed f16 ----
        unsigned hd[8];
        #pragma unroll
        for (int l = 0; l < NLVL; ++l) {
            const float rf = res.r[l];
            float fx = px * rf, fy = py * rf, fz = pz * rf;
            float bx = floorf(fx), by = floorf(fy), bz = floorf(fz);
            UH2 wxp, wyp, wzp;
            wxp.h = __builtin_amdgcn_cvt_pkrtz(fx - bx, fx - bx);
            wyp.h = __builtin_amdgcn_cvt_pkrtz(fy - by, fy - by);
            wzp.h = __builtin_amdgcn_cvt_pkrtz(fz - bz, fz - bz);
            unsigned ix = (unsigned)bx, iy = (unsigned)by, iz = (unsigned)bz;
            unsigned x0 = (ix << 2) & 4092u,          x1 = (x0 + 4u) & 4092u;
            unsigned y0 = ((iy * PR1) << 2) & 4092u,  y1 = (y0 + (PR1 << 2)) & 4092u;
            unsigned z0 = ((iz * PR2) << 2) & 4092u,  z1 = (z0 + (PR2 << 2)) & 4092u;
            unsigned a00 = x0 ^ y0, a01 = x0 ^ y1, a10 = x1 ^ y0, a11 = x1 ^ y1;
            const char* tlb = tabb + (l << 12);
            UH2 c000, c001, c010, c011, c100, c101, c110, c111;
            c000.u = *(const unsigned*)(tlb + (a00 ^ z0));
            c001.u = *(const unsigned*)(tlb + (a00 ^ z1));
            c010.u = *(const unsigned*)(tlb + (a01 ^ z0));
            c011.u = *(const unsigned*)(tlb + (a01 ^ z1));
            c100.u = *(const unsigned*)(tlb + (a10 ^ z0));
            c101.u = *(const unsigned*)(tlb + (a10 ^ z1));
            c110.u = *(const unsigned*)(tlb + (a11 ^ z0));
            c111.u = *(const unsigned*)(tlb + (a11 ^ z1));
            h2v zz00 = lerp2(c000.h, c001.h, wzp.h);
            h2v zz01 = lerp2(c010.h, c011.h, wzp.h);
            h2v zz10 = lerp2(c100.h, c101.h, wzp.h);
            h2v zz11 = lerp2(c110.h, c111.h, wzp.h);
            h2v yy0  = lerp2(zz00, zz01, wyp.h);
            h2v yy1  = lerp2(zz10, zz11, wyp.h);
            UH2 r; r.h = lerp2(yy0, yy1, wxp.h);
            hd[l] = r.u;                     // packed features (2l, 2l+1)
        }
        {   // encode->MLP transpose staging, stride 10 (4 b64 writes, <=4-way)
            unsigned* hp = hs + lane * 10;
            *(uint2*)&hp[0] = make_uint2(hd[0], hd[1]);
            *(uint2*)&hp[2] = make_uint2(hd[2], hd[3]);
            *(uint2*)&hp[4] = make_uint2(hd[4], hd[5]);
            *(uint2*)&hp[6] = make_uint2(hd[6], hd[7]);
        }

        // ---- MLP: 4 tiles of 16 points, 2 tiles in flight (register budget) ----
        #pragma unroll 2
        for (int t = 0; t < 4; ++t) {
            half4 b1 = as_h4(*(const uint2*)&hs[(t * 16 + m16) * 10 + 2 * q]);

            // L1: 16->64, relu (4 independent MFMAs)
            half4 b2[4];
            #pragma unroll
            for (int mo = 0; mo < 4; ++mo) {
                floatx4 c = MFMA16(A1[mo], b1, cz);
                b2[mo] = as_h4(make_uint2(pkrelu(c[0], c[1]), pkrelu(c[2], c[3])));
            }
            // L2: 64->16 linear; 2 parallel accumulation chains + add
            floatx4 c2a = MFMA16(A2[0], b2[0], cz);
            floatx4 c2b = MFMA16(A2[1], b2[1], cz);
            c2a = MFMA16(A2[2], b2[2], c2a);
            c2b = MFMA16(A2[3], b2[3], c2b);
            floatx4 c2 = c2a + c2b;
            half4 b3 = as_h4(make_uint2(pk2(c2[0], c2[1]), pk2(c2[2], c2[3])));

            // L3: 16->64, relu
            half4 b4[4];
            #pragma unroll
            for (int mo = 0; mo < 4; ++mo) {
                floatx4 c = MFMA16(A3[mo], b3, cz);
                b4[mo] = as_h4(make_uint2(pkrelu(c[0], c[1]), pkrelu(c[2], c[3])));
            }
            // L4: 64->64 relu fused with L5 dot(r3); 2 parallel chains per mo
            float z = 0.f;
            #pragma unroll
            for (int mo = 0; mo < 4; ++mo) {
                floatx4 ca = MFMA16(A4[0][mo], b4[0], cz);
                floatx4 cb = MFMA16(A4[1][mo], b4[1], cz);
                ca = MFMA16(A4[2][mo], b4[2], ca);
                cb = MFMA16(A4[3][mo], b4[3], cb);
                floatx4 c = ca + cb;
                #pragma unroll
                for (int r = 0; r < 4; ++r)
                    z = fmaf(fmaxf(c[r], 0.f), r3v[mo * 4 + r], z);
            }
            z += __shfl_xor(z, 16);
            z += __shfl_xor(z, 32);
            if (lane < 16)
                out[pbase + wv * 64 + t * 16 + lane] = 1.0f / (1.0f + __expf(-z));
        }
    }
}

extern "C" void kernel_launch(void* const* d_in, const int* in_sizes, int n_in,
                              void* d_out, int out_size, void* d_ws, size_t ws_size,
                              hipStream_t stream)
{
    const float* x  = (const float*)d_in[0];
    const float* tb = (const float*)d_in[1];
    const float* w1 = (const float*)d_in[2];
    const float* w2 = (const float*)d_in[3];
    const float* r1 = (const float*)d_in[4];
    const float* r2 = (const float*)d_in[5];
    const float* r3 = (const float*)d_in[6];
    float* out = (float*)d_out;
    const int N = in_sizes[0] / 3;

    // Replicate numpy: B_SCALE = exp(log(20*0.5/2)/(L-1)); RES = floor(2*B^l)
    Res8 res;
    double b = exp(log(20.0 * 0.5 / 2.0) / (double)(NLVL - 1));
    for (int l = 0; l < NLVL; ++l)
        res.r[l] = (float)floor(2.0 * pow(b, (double)l));

    // 1024 blocks x 512 thr x 4 iters == 2M exactly. 52KB LDS -> 2 blocks/CU.
    const int blocks = 1024, threads = 512;
    const int iters = N / (blocks * threads);
    ngp_mfma_kernel<<<blocks, threads, 0, stream>>>(x, tb, w1, w2, r1, r2, r3,
                                                    out, N, iters, res);
}

// Round 10
// 144.702 us; speedup vs baseline: 1.0685x; 1.0685x over previous
//
#include <hip/hip_runtime.h>
#include <math.h>

#define NLVL 8
#define PR1 2654435761u
#define PR2 805459861u

typedef __fp16    h2v   __attribute__((ext_vector_type(2)));   // cvt_pkrtz return type
typedef _Float16  half4 __attribute__((ext_vector_type(4)));   // 16x16x16 MFMA A/B operand
typedef float     floatx4 __attribute__((ext_vector_type(4)));

// Legacy K=16 MFMA builtins use the no-underscore dtype suffix on gfx950.
#define MFMA16(a,b,c) __builtin_amdgcn_mfma_f32_16x16x16f16(a,b,c,0,0,0)

union UH2 { unsigned u; h2v h; };

struct Res8 { float r[NLVL]; };

__device__ __forceinline__ unsigned pk2(float a, float b) {
    UH2 c; c.h = __builtin_amdgcn_cvt_pkrtz(a, b); return c.u;
}
__device__ __forceinline__ unsigned pkrelu(float a, float b) {
    UH2 c; c.h = __builtin_amdgcn_cvt_pkrtz(a, b);
    h2v z = {(__fp16)0.f, (__fp16)0.f};
    c.h = __builtin_elementwise_max(c.h, z);
    return c.u;
}
__device__ __forceinline__ half4 as_h4(uint2 u) {
    union { uint2 u; half4 h; } c; c.u = u; return c.h;
}
__device__ __forceinline__ h2v lerp2(h2v a, h2v b, h2v t) {
    return a + t * (b - a);
}

// Fused NGP, register-resident MLP chain (C/D frag of 16x16x16f16 == B frag of
// the next K=16 chunk -> inter-layer transpose is 2x cvt_pkrtz, zero LDS
// between layers). Round-10: live-set trimmed to fit the 128-reg (64 VGPR +
// 64 AGPR) budget of launch_bounds(512,4) WITHOUT scratch spills:
// t-loop unroll 1, r3 packed f16x2 (8 regs), hd written through every 2 levels.
__global__ __launch_bounds__(512, 4)
void ngp_mfma_kernel(const float* __restrict__ x,
                     const float* __restrict__ table,
                     const float* __restrict__ w1,
                     const float* __restrict__ w2,
                     const float* __restrict__ r1,
                     const float* __restrict__ r2,
                     const float* __restrict__ r3,
                     float* __restrict__ out,
                     int N, int iters, Res8 res)
{
    __shared__ unsigned tab[NLVL * 1024];   // 32 KB packed f16x2
    __shared__ unsigned hstg[8][640];       // 20 KB: 64 pts x 10 dw (stride-10 pad)

    const int tid  = threadIdx.x;
    const int lane = tid & 63, wv = tid >> 6;
    const int m16  = lane & 15, q = lane >> 4;

    {   // stage table: 8192 float2 -> 8192 packed dwords (16/thread @ 512 thr)
        const float2* src = (const float2*)table;
        #pragma unroll
        for (int k = 0; k < 16; ++k) {
            int i = tid + 512 * k;
            float2 v = src[i];
            tab[i] = pk2(v.x, v.y);
        }
    }

    // Preload weight A-frags (W^T) for 16x16x16: A[m=m16][k=q*4+j]. 56 regs
    // (AGPR-eligible: MFMA reads A operands from AGPRs on gfx950).
    half4 A1[4], A2[4], A3[4], A4[4][4];
    #pragma unroll
    for (int mo = 0; mo < 4; ++mo)
        #pragma unroll
        for (int j = 0; j < 4; ++j) {
            int k = q * 4 + j;
            A1[mo][j] = (_Float16)w1[k * 64 + mo * 16 + m16];
            A3[mo][j] = (_Float16)r1[k * 64 + mo * 16 + m16];
            A2[mo][j] = (_Float16)w2[(mo * 16 + k) * 16 + m16];   // mo = K-chunk here
            #pragma unroll
            for (int kc = 0; kc < 4; ++kc)
                A4[kc][mo][j] = (_Float16)r2[(kc * 16 + k) * 64 + mo * 16 + m16];
        }
    unsigned r3p[8];                        // r3 packed f16x2: 8 regs not 16
    #pragma unroll
    for (int mo = 0; mo < 4; ++mo) {
        r3p[mo * 2 + 0] = pk2(r3[mo * 16 + q * 4 + 0], r3[mo * 16 + q * 4 + 1]);
        r3p[mo * 2 + 1] = pk2(r3[mo * 16 + q * 4 + 2], r3[mo * 16 + q * 4 + 3]);
    }

    __syncthreads();                        // table visible; only barrier in kernel

    unsigned* hs = hstg[wv];
    const char* tabb = (const char*)tab;
    const floatx4 cz = {0.f, 0.f, 0.f, 0.f};

    #pragma unroll 1
    for (int it = 0; it < iters; ++it) {
        const int pbase = (it * (int)gridDim.x + (int)blockIdx.x) * 512;
        int p = pbase + tid;                 // grid*threads*iters == N exactly

        float px = x[3 * p + 0] + 0.5f;
        float py = x[3 * p + 1] + 0.5f;
        float pz = x[3 * p + 2] + 0.5f;

        // ---- encode: 8 levels, 7-lerp trilinear tree on packed f16.
        // Results written through to LDS every 2 levels (keeps hd live = 2).
        unsigned hd_prev = 0u;
        #pragma unroll
        for (int l = 0; l < NLVL; ++l) {
            const float rf = res.r[l];
            float fx = px * rf, fy = py * rf, fz = pz * rf;
            float bx = floorf(fx), by = floorf(fy), bz = floorf(fz);
            UH2 wxp, wyp, wzp;
            wxp.h = __builtin_amdgcn_cvt_pkrtz(fx - bx, fx - bx);
            wyp.h = __builtin_amdgcn_cvt_pkrtz(fy - by, fy - by);
            wzp.h = __builtin_amdgcn_cvt_pkrtz(fz - bz, fz - bz);
            unsigned ix = (unsigned)bx, iy = (unsigned)by, iz = (unsigned)bz;
            unsigned x0 = (ix << 2) & 4092u,          x1 = (x0 + 4u) & 4092u;
            unsigned y0 = ((iy * PR1) << 2) & 4092u,  y1 = (y0 + (PR1 << 2)) & 4092u;
            unsigned z0 = ((iz * PR2) << 2) & 4092u,  z1 = (z0 + (PR2 << 2)) & 4092u;
            unsigned a00 = x0 ^ y0, a01 = x0 ^ y1, a10 = x1 ^ y0, a11 = x1 ^ y1;
            const char* tlb = tabb + (l << 12);
            UH2 c000, c001, c010, c011, c100, c101, c110, c111;
            c000.u = *(const unsigned*)(tlb + (a00 ^ z0));
            c001.u = *(const unsigned*)(tlb + (a00 ^ z1));
            c010.u = *(const unsigned*)(tlb + (a01 ^ z0));
            c011.u = *(const unsigned*)(tlb + (a01 ^ z1));
            c100.u = *(const unsigned*)(tlb + (a10 ^ z0));
            c101.u = *(const unsigned*)(tlb + (a10 ^ z1));
            c110.u = *(const unsigned*)(tlb + (a11 ^ z0));
            c111.u = *(const unsigned*)(tlb + (a11 ^ z1));
            h2v zz00 = lerp2(c000.h, c001.h, wzp.h);
            h2v zz01 = lerp2(c010.h, c011.h, wzp.h);
            h2v zz10 = lerp2(c100.h, c101.h, wzp.h);
            h2v zz11 = lerp2(c110.h, c111.h, wzp.h);
            h2v yy0  = lerp2(zz00, zz01, wyp.h);
            h2v yy1  = lerp2(zz10, zz11, wyp.h);
            UH2 r; r.h = lerp2(yy0, yy1, wxp.h);
            if (l & 1)
                *(uint2*)&hs[lane * 10 + (l - 1)] = make_uint2(hd_prev, r.u);
            else
                hd_prev = r.u;
        }

        // ---- MLP: 4 tiles of 16 points, one tile in flight (register budget) ----
        #pragma unroll 1
        for (int t = 0; t < 4; ++t) {
            half4 b1 = as_h4(*(const uint2*)&hs[(t * 16 + m16) * 10 + 2 * q]);

            // L1: 16->64, relu (4 independent MFMAs)
            half4 b2[4];
            #pragma unroll
            for (int mo = 0; mo < 4; ++mo) {
                floatx4 c = MFMA16(A1[mo], b1, cz);
                b2[mo] = as_h4(make_uint2(pkrelu(c[0], c[1]), pkrelu(c[2], c[3])));
            }
            // L2: 64->16 linear; 2 parallel accumulation chains + add
            floatx4 c2a = MFMA16(A2[0], b2[0], cz);
            floatx4 c2b = MFMA16(A2[1], b2[1], cz);
            c2a = MFMA16(A2[2], b2[2], c2a);
            c2b = MFMA16(A2[3], b2[3], c2b);
            floatx4 c2 = c2a + c2b;
            half4 b3 = as_h4(make_uint2(pk2(c2[0], c2[1]), pk2(c2[2], c2[3])));

            // L3: 16->64, relu
            half4 b4[4];
            #pragma unroll
            for (int mo = 0; mo < 4; ++mo) {
                floatx4 c = MFMA16(A3[mo], b3, cz);
                b4[mo] = as_h4(make_uint2(pkrelu(c[0], c[1]), pkrelu(c[2], c[3])));
            }
            // L4: 64->64 relu fused with L5 dot(r3); 2 parallel chains per mo
            float z = 0.f;
            #pragma unroll
            for (int mo = 0; mo < 4; ++mo) {
                floatx4 ca = MFMA16(A4[0][mo], b4[0], cz);
                floatx4 cb = MFMA16(A4[1][mo], b4[1], cz);
                ca = MFMA16(A4[2][mo], b4[2], ca);
                cb = MFMA16(A4[3][mo], b4[3], cb);
                floatx4 c = ca + cb;
                UH2 ra, rb; ra.u = r3p[mo * 2 + 0]; rb.u = r3p[mo * 2 + 1];
                z = fmaf(fmaxf(c[0], 0.f), (float)ra.h[0], z);
                z = fmaf(fmaxf(c[1], 0.f), (float)ra.h[1], z);
                z = fmaf(fmaxf(c[2], 0.f), (float)rb.h[0], z);
                z = fmaf(fmaxf(c[3], 0.f), (float)rb.h[1], z);
            }
            z += __shfl_xor(z, 16);
            z += __shfl_xor(z, 32);
            if (lane < 16)
                out[pbase + wv * 64 + t * 16 + lane] = 1.0f / (1.0f + __expf(-z));
        }
    }
}

extern "C" void kernel_launch(void* const* d_in, const int* in_sizes, int n_in,
                              void* d_out, int out_size, void* d_ws, size_t ws_size,
                              hipStream_t stream)
{
    const float* x  = (const float*)d_in[0];
    const float* tb = (const float*)d_in[1];
    const float* w1 = (const float*)d_in[2];
    const float* w2 = (const float*)d_in[3];
    const float* r1 = (const float*)d_in[4];
    const float* r2 = (const float*)d_in[5];
    const float* r3 = (const float*)d_in[6];
    float* out = (float*)d_out;
    const int N = in_sizes[0] / 3;

    // Replicate numpy: B_SCALE = exp(log(20*0.5/2)/(L-1)); RES = floor(2*B^l)
    Res8 res;
    double b = exp(log(20.0 * 0.5 / 2.0) / (double)(NLVL - 1));
    for (int l = 0; l < NLVL; ++l)
        res.r[l] = (float)floor(2.0 * pow(b, (double)l));

    // 1024 blocks x 512 thr x 4 iters == 2M exactly. 52KB LDS -> 2 blocks/CU.
    const int blocks = 1024, threads = 512;
    const int iters = N / (blocks * threads);
    ngp_mfma_kernel<<<blocks, threads, 0, stream>>>(x, tb, w1, w2, r1, r2, r3,
                                                    out, N, iters, res);
}

// Round 11
// 142.376 us; speedup vs baseline: 1.0859x; 1.0163x over previous
//
#include <hip/hip_runtime.h>
#include <math.h>

#define NLVL 8
#define PR1 2654435761u
#define PR2 805459861u

typedef __fp16    h2v   __attribute__((ext_vector_type(2)));   // cvt_pkrtz return type
typedef _Float16  half4 __attribute__((ext_vector_type(4)));   // 16x16x16 MFMA A/B operand
typedef float     floatx4 __attribute__((ext_vector_type(4)));

// Legacy K=16 MFMA builtins use the no-underscore dtype suffix on gfx950.
#define MFMA16(a,b,c) __builtin_amdgcn_mfma_f32_16x16x16f16(a,b,c,0,0,0)

union UH2 { unsigned u; h2v h; };

struct Res8 { float r[NLVL]; };

__device__ __forceinline__ unsigned pk2(float a, float b) {
    UH2 c; c.h = __builtin_amdgcn_cvt_pkrtz(a, b); return c.u;
}
__device__ __forceinline__ unsigned pkrelu(float a, float b) {
    UH2 c; c.h = __builtin_amdgcn_cvt_pkrtz(a, b);
    h2v z = {(__fp16)0.f, (__fp16)0.f};
    c.h = __builtin_elementwise_max(c.h, z);
    return c.u;
}
__device__ __forceinline__ half4 as_h4(uint2 u) {
    union { uint2 u; half4 h; } c; c.u = u; return c.h;
}
__device__ __forceinline__ h2v lerp2(h2v a, h2v b, h2v t) {
    return a + t * (b - a);
}

// Fused NGP, register-resident MLP chain (C/D frag of 16x16x16f16 == B frag of
// the next K=16 chunk -> inter-layer transpose is 2x cvt_pkrtz).
// Round-11: the persistent weight set (56 regs) was overflowing the 128-reg
// (64 VGPR + 64 AGPR) budget at 4 waves/EU -> ~26MB/launch scratch traffic
// (r8-r10 WRITE_SIZE 31-51MB vs 8.2MB of output). Fix: A4 (r2, 32 regs) is
// streamed from LDS in pre-swizzled frag order (conflict-free b64 reads, 8KB);
// an asm memory clobber per tile stops LICM from hoisting it back to regs.
__global__ __launch_bounds__(512, 4)
void ngp_mfma_kernel(const float* __restrict__ x,
                     const float* __restrict__ table,
                     const float* __restrict__ w1,
                     const float* __restrict__ w2,
                     const float* __restrict__ r1,
                     const float* __restrict__ r2,
                     const float* __restrict__ r3,
                     float* __restrict__ out,
                     int N, int iters, Res8 res)
{
    __shared__ unsigned tab[NLVL * 1024];   // 32 KB packed f16x2
    __shared__ unsigned hstg[8][640];       // 20 KB: 64 pts x 10 dw (stride-10 pad)
    __shared__ unsigned r2s[2048];          // 8 KB: r2 in frag order, uint2/lane

    const int tid  = threadIdx.x;
    const int lane = tid & 63, wv = tid >> 6;
    const int m16  = lane & 15, q = lane >> 4;

    {   // stage table: 8192 float2 -> 8192 packed dwords (16/thread @ 512 thr)
        const float2* src = (const float2*)table;
        #pragma unroll
        for (int k = 0; k < 16; ++k) {
            int i = tid + 512 * k;
            float2 v = src[i];
            tab[i] = pk2(v.x, v.y);
        }
    }
    {   // stage r2 pre-swizzled: frag fid=(kc*4+mo), lane ln -> uint2 of 4 f16
        #pragma unroll
        for (int pi = tid; pi < 1024; pi += 512) {
            int ln = pi & 63, fid = pi >> 6;
            int kc = fid >> 2, mo = fid & 3;
            int m = ln & 15, qq = ln >> 4;
            const float* rr = r2 + (kc * 16 + qq * 4) * 64 + mo * 16 + m;
            r2s[pi * 2 + 0] = pk2(rr[0],   rr[64]);
            r2s[pi * 2 + 1] = pk2(rr[128], rr[192]);
        }
    }

    // Persistent frags: A1,A2,A3 (24 regs) + r3 packed (8 regs) = 32 regs.
    half4 A1[4], A2[4], A3[4];
    #pragma unroll
    for (int mo = 0; mo < 4; ++mo)
        #pragma unroll
        for (int j = 0; j < 4; ++j) {
            int k = q * 4 + j;
            A1[mo][j] = (_Float16)w1[k * 64 + mo * 16 + m16];
            A3[mo][j] = (_Float16)r1[k * 64 + mo * 16 + m16];
            A2[mo][j] = (_Float16)w2[(mo * 16 + k) * 16 + m16];   // mo = K-chunk here
        }
    unsigned r3p[8];
    #pragma unroll
    for (int mo = 0; mo < 4; ++mo) {
        r3p[mo * 2 + 0] = pk2(r3[mo * 16 + q * 4 + 0], r3[mo * 16 + q * 4 + 1]);
        r3p[mo * 2 + 1] = pk2(r3[mo * 16 + q * 4 + 2], r3[mo * 16 + q * 4 + 3]);
    }

    __syncthreads();                        // table+r2s visible; only barrier

    unsigned* hs = hstg[wv];
    const char* tabb = (const char*)tab;
    const floatx4 cz = {0.f, 0.f, 0.f, 0.f};

    #pragma unroll 1
    for (int it = 0; it < iters; ++it) {
        const int pbase = (it * (int)gridDim.x + (int)blockIdx.x) * 512;
        int p = pbase + tid;                 // grid*threads*iters == N exactly

        float px = x[3 * p + 0] + 0.5f;
        float py = x[3 * p + 1] + 0.5f;
        float pz = x[3 * p + 2] + 0.5f;

        // ---- encode: 8 levels, 7-lerp trilinear tree on packed f16.
        // Written through to LDS every 2 levels (keeps hd live = 2).
        unsigned hd_prev = 0u;
        #pragma unroll
        for (int l = 0; l < NLVL; ++l) {
            const float rf = res.r[l];
            float fx = px * rf, fy = py * rf, fz = pz * rf;
            float bx = floorf(fx), by = floorf(fy), bz = floorf(fz);
            UH2 wxp, wyp, wzp;
            wxp.h = __builtin_amdgcn_cvt_pkrtz(fx - bx, fx - bx);
            wyp.h = __builtin_amdgcn_cvt_pkrtz(fy - by, fy - by);
            wzp.h = __builtin_amdgcn_cvt_pkrtz(fz - bz, fz - bz);
            unsigned ix = (unsigned)bx, iy = (unsigned)by, iz = (unsigned)bz;
            unsigned x0 = (ix << 2) & 4092u,          x1 = (x0 + 4u) & 4092u;
            unsigned y0 = ((iy * PR1) << 2) & 4092u,  y1 = (y0 + (PR1 << 2)) & 4092u;
            unsigned z0 = ((iz * PR2) << 2) & 4092u,  z1 = (z0 + (PR2 << 2)) & 4092u;
            unsigned a00 = x0 ^ y0, a01 = x0 ^ y1, a10 = x1 ^ y0, a11 = x1 ^ y1;
            const char* tlb = tabb + (l << 12);
            UH2 c000, c001, c010, c011, c100, c101, c110, c111;
            c000.u = *(const unsigned*)(tlb + (a00 ^ z0));
            c001.u = *(const unsigned*)(tlb + (a00 ^ z1));
            c010.u = *(const unsigned*)(tlb + (a01 ^ z0));
            c011.u = *(const unsigned*)(tlb + (a01 ^ z1));
            c100.u = *(const unsigned*)(tlb + (a10 ^ z0));
            c101.u = *(const unsigned*)(tlb + (a10 ^ z1));
            c110.u = *(const unsigned*)(tlb + (a11 ^ z0));
            c111.u = *(const unsigned*)(tlb + (a11 ^ z1));
            h2v zz00 = lerp2(c000.h, c001.h, wzp.h);
            h2v zz01 = lerp2(c010.h, c011.h, wzp.h);
            h2v zz10 = lerp2(c100.h, c101.h, wzp.h);
            h2v zz11 = lerp2(c110.h, c111.h, wzp.h);
            h2v yy0  = lerp2(zz00, zz01, wyp.h);
            h2v yy1  = lerp2(zz10, zz11, wyp.h);
            UH2 r; r.h = lerp2(yy0, yy1, wxp.h);
            if (l & 1)
                *(uint2*)&hs[lane * 10 + (l - 1)] = make_uint2(hd_prev, r.u);
            else
                hd_prev = r.u;
        }

        // ---- MLP: 4 tiles of 16 points ----
        #pragma unroll 1
        for (int t = 0; t < 4; ++t) {
            // Memory clobber: keep the per-tile r2s frag loads INSIDE the loop
            // (LICM would hoist all 16 -> +32 regs -> the spills come back).
            asm volatile("" ::: "memory");

            half4 b1 = as_h4(*(const uint2*)&hs[(t * 16 + m16) * 10 + 2 * q]);

            // L1: 16->64, relu (4 independent MFMAs)
            half4 b2[4];
            #pragma unroll
            for (int mo = 0; mo < 4; ++mo) {
                floatx4 c = MFMA16(A1[mo], b1, cz);
                b2[mo] = as_h4(make_uint2(pkrelu(c[0], c[1]), pkrelu(c[2], c[3])));
            }
            // L2: 64->16 linear; 2 parallel accumulation chains + add
            floatx4 c2a = MFMA16(A2[0], b2[0], cz);
            floatx4 c2b = MFMA16(A2[1], b2[1], cz);
            c2a = MFMA16(A2[2], b2[2], c2a);
            c2b = MFMA16(A2[3], b2[3], c2b);
            floatx4 c2 = c2a + c2b;
            half4 b3 = as_h4(make_uint2(pk2(c2[0], c2[1]), pk2(c2[2], c2[3])));

            // L3: 16->64, relu
            half4 b4[4];
            #pragma unroll
            for (int mo = 0; mo < 4; ++mo) {
                floatx4 c = MFMA16(A3[mo], b3, cz);
                b4[mo] = as_h4(make_uint2(pkrelu(c[0], c[1]), pkrelu(c[2], c[3])));
            }
            // L4: 64->64 relu fused with L5 dot(r3); A4 frags streamed from LDS
            float z = 0.f;
            #pragma unroll
            for (int mo = 0; mo < 4; ++mo) {
                half4 a40 = as_h4(*(const uint2*)&r2s[((0 * 4 + mo) * 64 + lane) * 2]);
                half4 a41 = as_h4(*(const uint2*)&r2s[((1 * 4 + mo) * 64 + lane) * 2]);
                half4 a42 = as_h4(*(const uint2*)&r2s[((2 * 4 + mo) * 64 + lane) * 2]);
                half4 a43 = as_h4(*(const uint2*)&r2s[((3 * 4 + mo) * 64 + lane) * 2]);
                floatx4 ca = MFMA16(a40, b4[0], cz);
                floatx4 cb = MFMA16(a41, b4[1], cz);
                ca = MFMA16(a42, b4[2], ca);
                cb = MFMA16(a43, b4[3], cb);
                floatx4 c = ca + cb;
                UH2 ra, rb; ra.u = r3p[mo * 2 + 0]; rb.u = r3p[mo * 2 + 1];
                z = fmaf(fmaxf(c[0], 0.f), (float)ra.h[0], z);
                z = fmaf(fmaxf(c[1], 0.f), (float)ra.h[1], z);
                z = fmaf(fmaxf(c[2], 0.f), (float)rb.h[0], z);
                z = fmaf(fmaxf(c[3], 0.f), (float)rb.h[1], z);
            }
            z += __shfl_xor(z, 16);
            z += __shfl_xor(z, 32);
            if (lane < 16)
                out[pbase + wv * 64 + t * 16 + lane] = 1.0f / (1.0f + __expf(-z));
        }
    }
}

extern "C" void kernel_launch(void* const* d_in, const int* in_sizes, int n_in,
                              void* d_out, int out_size, void* d_ws, size_t ws_size,
                              hipStream_t stream)
{
    const float* x  = (const float*)d_in[0];
    const float* tb = (const float*)d_in[1];
    const float* w1 = (const float*)d_in[2];
    const float* w2 = (const float*)d_in[3];
    const float* r1 = (const float*)d_in[4];
    const float* r2 = (const float*)d_in[5];
    const float* r3 = (const float*)d_in[6];
    float* out = (float*)d_out;
    const int N = in_sizes[0] / 3;

    // Replicate numpy: B_SCALE = exp(log(20*0.5/2)/(L-1)); RES = floor(2*B^l)
    Res8 res;
    double b = exp(log(20.0 * 0.5 / 2.0) / (double)(NLVL - 1));
    for (int l = 0; l < NLVL; ++l)
        res.r[l] = (float)floor(2.0 * pow(b, (double)l));

    // 1024 blocks x 512 thr x 4 iters == 2M exactly. 60KB LDS -> 2 blocks/CU.
    const int blocks = 1024, threads = 512;
    const int iters = N / (blocks * threads);
    ngp_mfma_kernel<<<blocks, threads, 0, stream>>>(x, tb, w1, w2, r1, r2, r3,
                                                    out, N, iters, res);
}

// Round 13
// 137.358 us; speedup vs baseline: 1.1256x; 1.0365x over previous
//
#include <hip/hip_runtime.h>
#include <math.h>

#define NLVL 8
#define PR1 2654435761u
#define PR2 805459861u

typedef __fp16    f16x2 __attribute__((ext_vector_type(2)));   // cvt_pkrtz return type
typedef _Float16  half4 __attribute__((ext_vector_type(4)));   // 16x16x16 MFMA operand
typedef _Float16  half8 __attribute__((ext_vector_type(8)));   // 16x16x32 MFMA operand
typedef float     floatx4 __attribute__((ext_vector_type(4)));

#define MFMA16(a,b,c) __builtin_amdgcn_mfma_f32_16x16x16f16(a,b,c,0,0,0)
#define MFMA32(a,b,c) __builtin_amdgcn_mfma_f32_16x16x32_f16(a,b,c,0,0,0)

union UH2 { unsigned u; f16x2 f; };

struct Res8 { float r[NLVL]; };

__device__ __forceinline__ unsigned pk2(float a, float b) {
    UH2 c; c.f = __builtin_amdgcn_cvt_pkrtz(a, b); return c.u;
}
__device__ __forceinline__ unsigned pkrelu(float a, float b) {
    UH2 c; c.f = __builtin_amdgcn_cvt_pkrtz(a, b);
    f16x2 z = {(__fp16)0.f, (__fp16)0.f};
    c.f = __builtin_elementwise_max(c.f, z);                   // v_pk_max_f16
    return c.u;
}
__device__ __forceinline__ half4 as_h4(uint2 u) {
    union { uint2 u; half4 h; } c; c.u = u; return c.h;
}
__device__ __forceinline__ half8 as_h8(uint4 u) {
    union { uint4 u; half8 h; } c; c.u = u; return c.h;
}
__device__ __forceinline__ f16x2 lerp2(f16x2 a, f16x2 b, f16x2 t) {
    return a + t * (b - a);                                    // v_pk_sub + v_pk_fma
}
// Row permutation enabling K=32 consumption of K=16 chunk outputs:
// chunk mo (=2*kc+b), local row m (=4*qm+r) -> global row 32*kc + 8*qm + 4*b + r.
// With this, concat(C[2kc], C[2kc+1]) per lane IS the natural K=32 B-frag, and
// the consumer's A-frag is loaded with NO permutation.
__device__ __forceinline__ int grow(int mo, int m) {
    return 32 * (mo >> 1) + (m >> 2) * 8 + 4 * (mo & 1) + (m & 3);
}

// Fused NGP: LDS hash-grid encode + register-resident MFMA MLP.
// r13 (= r12 minus __half2 intrinsics): L2/L4 on native K=32 MFMA (18 vs 24
// MFMA slots/tile, chain adds gone, A4 reads b128); A4 streamed from LDS
// (persistent regs = 32 -> no spills, r11's fix). 60KB LDS -> 2 blocks/CU.
__global__ __launch_bounds__(512, 4)
void ngp_mfma_kernel(const float* __restrict__ x,
                     const float* __restrict__ table,
                     const float* __restrict__ w1,
                     const float* __restrict__ w2,
                     const float* __restrict__ r1,
                     const float* __restrict__ r2,
                     const float* __restrict__ r3,
                     float* __restrict__ out,
                     int N, int iters, Res8 res)
{
    __shared__ unsigned tab[NLVL * 1024];   // 32 KB packed f16x2
    __shared__ unsigned hstg[8][640];       // 20 KB: 64 pts x 10 dw (stride-10 pad)
    __shared__ uint4    r2s4[512];          // 8 KB: r2 as K32 A-frags, uint4/lane

    const int tid  = threadIdx.x;
    const int lane = tid & 63, wv = tid >> 6;
    const int m16  = lane & 15, q = lane >> 4;

    {   // stage table: 8192 float2 -> 8192 packed dwords
        const float2* src = (const float2*)table;
        #pragma unroll
        for (int k = 0; k < 16; ++k) {
            int i = tid + 512 * k;
            float2 v = src[i];
            tab[i] = pk2(v.x, v.y);
        }
    }
    {   // stage r2 as natural K32 A-frags: fid = kc*4+mo, one uint4 per lane
        int fid = tid >> 6, ln = tid & 63;
        int kc = fid >> 2, mo = fid & 3;
        int m = ln & 15, qq = ln >> 4;
        const float* rr = r2 + (kc * 32 + qq * 8) * 64 + mo * 16 + m;
        r2s4[tid] = make_uint4(pk2(rr[0],   rr[64]),  pk2(rr[128], rr[192]),
                               pk2(rr[256], rr[320]), pk2(rr[384], rr[448]));
    }

    // Persistent frags: A1,A3 (8+8 regs, permuted rows), A2 K32 (8), r3 (8).
    half4 A1[4], A3[4];
    half8 A2[2];
    #pragma unroll
    for (int mo = 0; mo < 4; ++mo) {
        int g = grow(mo, m16);
        #pragma unroll
        for (int j = 0; j < 4; ++j) {
            int k = q * 4 + j;
            A1[mo][j] = (_Float16)w1[k * 64 + g];
            A3[mo][j] = (_Float16)r1[k * 64 + g];
        }
    }
    #pragma unroll
    for (int kc = 0; kc < 2; ++kc)
        #pragma unroll
        for (int j = 0; j < 8; ++j)
            A2[kc][j] = (_Float16)w2[(kc * 32 + q * 8 + j) * 16 + m16];
    unsigned r3p[8];
    #pragma unroll
    for (int mo = 0; mo < 4; ++mo) {
        r3p[mo * 2 + 0] = pk2(r3[mo * 16 + q * 4 + 0], r3[mo * 16 + q * 4 + 1]);
        r3p[mo * 2 + 1] = pk2(r3[mo * 16 + q * 4 + 2], r3[mo * 16 + q * 4 + 3]);
    }

    __syncthreads();                        // table+r2s visible; only barrier

    unsigned* hs = hstg[wv];
    const char* tabb = (const char*)tab;
    const floatx4 cz = {0.f, 0.f, 0.f, 0.f};

    #pragma unroll 1
    for (int it = 0; it < iters; ++it) {
        const int pbase = (it * (int)gridDim.x + (int)blockIdx.x) * 512;
        int p = pbase + tid;                 // grid*threads*iters == N exactly

        float px = x[3 * p + 0] + 0.5f;
        float py = x[3 * p + 1] + 0.5f;
        float pz = x[3 * p + 2] + 0.5f;

        // ---- encode: 8 levels, 7-lerp trilinear tree on v_pk_*_f16 ----
        unsigned hd_prev = 0u;
        #pragma unroll
        for (int l = 0; l < NLVL; ++l) {
            const float rf = res.r[l];
            float fx = px * rf, fy = py * rf, fz = pz * rf;
            float bx = floorf(fx), by = floorf(fy), bz = floorf(fz);
            UH2 wxp, wyp, wzp;
            wxp.f = __builtin_amdgcn_cvt_pkrtz(fx - bx, fx - bx);
            wyp.f = __builtin_amdgcn_cvt_pkrtz(fy - by, fy - by);
            wzp.f = __builtin_amdgcn_cvt_pkrtz(fz - bz, fz - bz);
            unsigned ix = (unsigned)bx, iy = (unsigned)by, iz = (unsigned)bz;
            unsigned x0 = (ix << 2) & 4092u,          x1 = (x0 + 4u) & 4092u;
            unsigned y0 = ((iy * PR1) << 2) & 4092u,  y1 = (y0 + (PR1 << 2)) & 4092u;
            unsigned z0 = ((iz * PR2) << 2) & 4092u,  z1 = (z0 + (PR2 << 2)) & 4092u;
            unsigned a00 = x0 ^ y0, a01 = x0 ^ y1, a10 = x1 ^ y0, a11 = x1 ^ y1;
            const char* tlb = tabb + (l << 12);
            UH2 c000, c001, c010, c011, c100, c101, c110, c111;
            c000.u = *(const unsigned*)(tlb + (a00 ^ z0));
            c001.u = *(const unsigned*)(tlb + (a00 ^ z1));
            c010.u = *(const unsigned*)(tlb + (a01 ^ z0));
            c011.u = *(const unsigned*)(tlb + (a01 ^ z1));
            c100.u = *(const unsigned*)(tlb + (a10 ^ z0));
            c101.u = *(const unsigned*)(tlb + (a10 ^ z1));
            c110.u = *(const unsigned*)(tlb + (a11 ^ z0));
            c111.u = *(const unsigned*)(tlb + (a11 ^ z1));
            f16x2 zz00 = lerp2(c000.f, c001.f, wzp.f);
            f16x2 zz01 = lerp2(c010.f, c011.f, wzp.f);
            f16x2 zz10 = lerp2(c100.f, c101.f, wzp.f);
            f16x2 zz11 = lerp2(c110.f, c111.f, wzp.f);
            f16x2 yy0  = lerp2(zz00, zz01, wyp.f);
            f16x2 yy1  = lerp2(zz10, zz11, wyp.f);
            UH2 r; r.f = lerp2(yy0, yy1, wxp.f);
            if (l & 1)
                *(uint2*)&hs[lane * 10 + (l - 1)] = make_uint2(hd_prev, r.u);
            else
                hd_prev = r.u;
        }

        // ---- MLP: 4 tiles of 16 points ----
        #pragma unroll 1
        for (int t = 0; t < 4; ++t) {
            // keep per-tile r2s frag loads inside the loop (LICM -> +32 regs -> spills)
            asm volatile("" ::: "memory");

            half4 b1 = as_h4(*(const uint2*)&hs[(t * 16 + m16) * 10 + 2 * q]);

            // L1: 16->64, relu; output rows permuted per grow()
            uint2 b2u[4];
            #pragma unroll
            for (int mo = 0; mo < 4; ++mo) {
                floatx4 c = MFMA16(A1[mo], b1, cz);
                b2u[mo] = make_uint2(pkrelu(c[0], c[1]), pkrelu(c[2], c[3]));
            }
            // L2: 64->16 linear, native K=32 (B-frag = concat of chunk pairs)
            half8 bk20 = as_h8(make_uint4(b2u[0].x, b2u[0].y, b2u[1].x, b2u[1].y));
            half8 bk21 = as_h8(make_uint4(b2u[2].x, b2u[2].y, b2u[3].x, b2u[3].y));
            floatx4 c2 = MFMA32(A2[0], bk20, cz);
            c2 = MFMA32(A2[1], bk21, c2);
            half4 b3 = as_h4(make_uint2(pk2(c2[0], c2[1]), pk2(c2[2], c2[3])));

            // L3: 16->64, relu; rows permuted
            uint2 b4u[4];
            #pragma unroll
            for (int mo = 0; mo < 4; ++mo) {
                floatx4 c = MFMA16(A3[mo], b3, cz);
                b4u[mo] = make_uint2(pkrelu(c[0], c[1]), pkrelu(c[2], c[3]));
            }
            // L4: 64->64 relu + L5 dot(r3); native K=32, A4 streamed from LDS
            half8 bk40 = as_h8(make_uint4(b4u[0].x, b4u[0].y, b4u[1].x, b4u[1].y));
            half8 bk41 = as_h8(make_uint4(b4u[2].x, b4u[2].y, b4u[3].x, b4u[3].y));
            float z = 0.f;
            #pragma unroll
            for (int mo = 0; mo < 4; ++mo) {
                half8 a40 = as_h8(r2s4[(0 * 4 + mo) * 64 + lane]);
                half8 a41 = as_h8(r2s4[(1 * 4 + mo) * 64 + lane]);
                floatx4 c = MFMA32(a40, bk40, cz);
                c = MFMA32(a41, bk41, c);
                UH2 ra, rb; ra.u = r3p[mo * 2 + 0]; rb.u = r3p[mo * 2 + 1];
                z = fmaf(fmaxf(c[0], 0.f), (float)ra.f[0], z);
                z = fmaf(fmaxf(c[1], 0.f), (float)ra.f[1], z);
                z = fmaf(fmaxf(c[2], 0.f), (float)rb.f[0], z);
                z = fmaf(fmaxf(c[3], 0.f), (float)rb.f[1], z);
            }
            z += __shfl_xor(z, 16);
            z += __shfl_xor(z, 32);
            if (lane < 16)
                out[pbase + wv * 64 + t * 16 + lane] = 1.0f / (1.0f + __expf(-z));
        }
    }
}

extern "C" void kernel_launch(void* const* d_in, const int* in_sizes, int n_in,
                              void* d_out, int out_size, void* d_ws, size_t ws_size,
                              hipStream_t stream)
{
    const float* x  = (const float*)d_in[0];
    const float* tb = (const float*)d_in[1];
    const float* w1 = (const float*)d_in[2];
    const float* w2 = (const float*)d_in[3];
    const float* r1 = (const float*)d_in[4];
    const float* r2 = (const float*)d_in[5];
    const float* r3 = (const float*)d_in[6];
    float* out = (float*)d_out;
    const int N = in_sizes[0] / 3;

    // Replicate numpy: B_SCALE = exp(log(20*0.5/2)/(L-1)); RES = floor(2*B^l)
    Res8 res;
    double b = exp(log(20.0 * 0.5 / 2.0) / (double)(NLVL - 1));
    for (int l = 0; l < NLVL; ++l)
        res.r[l] = (float)floor(2.0 * pow(b, (double)l));

    // 1024 blocks x 512 thr x 4 iters == 2M exactly. 60KB LDS -> 2 blocks/CU.
    const int blocks = 1024, threads = 512;
    const int iters = N / (blocks * threads);
    ngp_mfma_kernel<<<blocks, threads, 0, stream>>>(x, tb, w1, w2, r1, r2, r3,
                                                    out, N, iters, res);
}

// Round 14
// 135.544 us; speedup vs baseline: 1.1407x; 1.0134x over previous
//
#include <hip/hip_runtime.h>
#include <math.h>

#define NLVL 8
#define PR1 2654435761u
#define PR2 805459861u

typedef __fp16    f16x2 __attribute__((ext_vector_type(2)));   // cvt_pkrtz return type
typedef _Float16  half4 __attribute__((ext_vector_type(4)));   // 16x16x16 MFMA operand
typedef _Float16  half8 __attribute__((ext_vector_type(8)));   // 16x16x32 MFMA operand
typedef float     floatx4 __attribute__((ext_vector_type(4)));

#define MFMA16(a,b,c) __builtin_amdgcn_mfma_f32_16x16x16f16(a,b,c,0,0,0)
#define MFMA32(a,b,c) __builtin_amdgcn_mfma_f32_16x16x32_f16(a,b,c,0,0,0)

union UH2 { unsigned u; f16x2 f; };

struct Res8 { float r[NLVL]; };

__device__ __forceinline__ unsigned pk2(float a, float b) {
    UH2 c; c.f = __builtin_amdgcn_cvt_pkrtz(a, b); return c.u;
}
__device__ __forceinline__ unsigned pkrelu(float a, float b) {
    UH2 c; c.f = __builtin_amdgcn_cvt_pkrtz(a, b);
    f16x2 z = {(__fp16)0.f, (__fp16)0.f};
    c.f = __builtin_elementwise_max(c.f, z);                   // v_pk_max_f16
    return c.u;
}
__device__ __forceinline__ half4 as_h4(uint2 u) {
    union { uint2 u; half4 h; } c; c.u = u; return c.h;
}
__device__ __forceinline__ half8 as_h8(uint4 u) {
    union { uint4 u; half8 h; } c; c.u = u; return c.h;
}
__device__ __forceinline__ f16x2 lerp2(f16x2 a, f16x2 b, f16x2 t) {
    return a + t * (b - a);                                    // v_pk_sub + v_pk_fma
}
// Row permutation enabling K=32 consumption of K=16 chunk outputs:
// chunk mo (=2*kc+b), local row m (=4*qm+r) -> global row 32*kc + 8*qm + 4*b + r.
__device__ __forceinline__ int grow(int mo, int m) {
    return 32 * (mo >> 1) + (m >> 2) * 8 + 4 * (mo & 1) + (m & 3);
}

// Fused NGP: LDS hash-grid encode + register-resident MFMA MLP.
// r14: hd stays in registers through the MLP; per tile only the 16 owning
// lanes (q==t) stage their 4 uint2s -> hstg shrinks 20KB -> 5KB ->
// 45KB/block -> 3 blocks/CU (24 waves/CU, 6/SIMD; was 16/CU). Stride-10
// staging is b64-aligned and conflict-free on both write and read sides.
__global__ __launch_bounds__(512, 4)
void ngp_mfma_kernel(const float* __restrict__ x,
                     const float* __restrict__ table,
                     const float* __restrict__ w1,
                     const float* __restrict__ w2,
                     const float* __restrict__ r1,
                     const float* __restrict__ r2,
                     const float* __restrict__ r3,
                     float* __restrict__ out,
                     int N, int iters, Res8 res)
{
    __shared__ unsigned tab[NLVL * 1024];   // 32 KB packed f16x2
    __shared__ unsigned hstg[8][160];       // 5 KB: 16 pts x 10 dw per wave
    __shared__ uint4    r2s4[512];          // 8 KB: r2 as K32 A-frags

    const int tid  = threadIdx.x;
    const int lane = tid & 63, wv = tid >> 6;
    const int m16  = lane & 15, q = lane >> 4;

    {   // stage table: 8192 float2 -> 8192 packed dwords
        const float2* src = (const float2*)table;
        #pragma unroll
        for (int k = 0; k < 16; ++k) {
            int i = tid + 512 * k;
            float2 v = src[i];
            tab[i] = pk2(v.x, v.y);
        }
    }
    {   // stage r2 as natural K32 A-frags: fid = kc*4+mo, one uint4 per lane
        int fid = tid >> 6, ln = tid & 63;
        int kc = fid >> 2, mo = fid & 3;
        int m = ln & 15, qq = ln >> 4;
        const float* rr = r2 + (kc * 32 + qq * 8) * 64 + mo * 16 + m;
        r2s4[tid] = make_uint4(pk2(rr[0],   rr[64]),  pk2(rr[128], rr[192]),
                               pk2(rr[256], rr[320]), pk2(rr[384], rr[448]));
    }

    // Persistent frags: A1,A3 (8+8 regs, permuted rows), A2 K32 (8), r3 (8).
    half4 A1[4], A3[4];
    half8 A2[2];
    #pragma unroll
    for (int mo = 0; mo < 4; ++mo) {
        int g = grow(mo, m16);
        #pragma unroll
        for (int j = 0; j < 4; ++j) {
            int k = q * 4 + j;
            A1[mo][j] = (_Float16)w1[k * 64 + g];
            A3[mo][j] = (_Float16)r1[k * 64 + g];
        }
    }
    #pragma unroll
    for (int kc = 0; kc < 2; ++kc)
        #pragma unroll
        for (int j = 0; j < 8; ++j)
            A2[kc][j] = (_Float16)w2[(kc * 32 + q * 8 + j) * 16 + m16];
    unsigned r3p[8];
    #pragma unroll
    for (int mo = 0; mo < 4; ++mo) {
        r3p[mo * 2 + 0] = pk2(r3[mo * 16 + q * 4 + 0], r3[mo * 16 + q * 4 + 1]);
        r3p[mo * 2 + 1] = pk2(r3[mo * 16 + q * 4 + 2], r3[mo * 16 + q * 4 + 3]);
    }

    __syncthreads();                        // table+r2s visible; only barrier

    unsigned* hs = hstg[wv];
    const char* tabb = (const char*)tab;
    const floatx4 cz = {0.f, 0.f, 0.f, 0.f};

    #pragma unroll 1
    for (int it = 0; it < iters; ++it) {
        const int pbase = (it * (int)gridDim.x + (int)blockIdx.x) * 512;
        int p = pbase + tid;                 // grid*threads*iters == N exactly

        float px = x[3 * p + 0] + 0.5f;
        float py = x[3 * p + 1] + 0.5f;
        float pz = x[3 * p + 2] + 0.5f;

        // ---- encode: 8 levels, 7-lerp trilinear tree; hd stays in regs ----
        unsigned hd[8];
        #pragma unroll
        for (int l = 0; l < NLVL; ++l) {
            const float rf = res.r[l];
            float fx = px * rf, fy = py * rf, fz = pz * rf;
            float bx = floorf(fx), by = floorf(fy), bz = floorf(fz);
            UH2 wxp, wyp, wzp;
            wxp.f = __builtin_amdgcn_cvt_pkrtz(fx - bx, fx - bx);
            wyp.f = __builtin_amdgcn_cvt_pkrtz(fy - by, fy - by);
            wzp.f = __builtin_amdgcn_cvt_pkrtz(fz - bz, fz - bz);
            unsigned ix = (unsigned)bx, iy = (unsigned)by, iz = (unsigned)bz;
            unsigned x0 = (ix << 2) & 4092u,          x1 = (x0 + 4u) & 4092u;
            unsigned y0 = ((iy * PR1) << 2) & 4092u,  y1 = (y0 + (PR1 << 2)) & 4092u;
            unsigned z0 = ((iz * PR2) << 2) & 4092u,  z1 = (z0 + (PR2 << 2)) & 4092u;
            unsigned a00 = x0 ^ y0, a01 = x0 ^ y1, a10 = x1 ^ y0, a11 = x1 ^ y1;
            const char* tlb = tabb + (l << 12);
            UH2 c000, c001, c010, c011, c100, c101, c110, c111;
            c000.u = *(const unsigned*)(tlb + (a00 ^ z0));
            c001.u = *(const unsigned*)(tlb + (a00 ^ z1));
            c010.u = *(const unsigned*)(tlb + (a01 ^ z0));
            c011.u = *(const unsigned*)(tlb + (a01 ^ z1));
            c100.u = *(const unsigned*)(tlb + (a10 ^ z0));
            c101.u = *(const unsigned*)(tlb + (a10 ^ z1));
            c110.u = *(const unsigned*)(tlb + (a11 ^ z0));
            c111.u = *(const unsigned*)(tlb + (a11 ^ z1));
            f16x2 zz00 = lerp2(c000.f, c001.f, wzp.f);
            f16x2 zz01 = lerp2(c010.f, c011.f, wzp.f);
            f16x2 zz10 = lerp2(c100.f, c101.f, wzp.f);
            f16x2 zz11 = lerp2(c110.f, c111.f, wzp.f);
            f16x2 yy0  = lerp2(zz00, zz01, wyp.f);
            f16x2 yy1  = lerp2(zz10, zz11, wyp.f);
            UH2 r; r.f = lerp2(yy0, yy1, wxp.f);
            hd[l] = r.u;                     // packed features (2l, 2l+1)
        }

        // ---- MLP: 4 tiles of 16 points; per tile, only lanes q==t stage ----
        #pragma unroll 1
        for (int t = 0; t < 4; ++t) {
            // keep per-tile r2s frag loads inside the loop (LICM -> spills)
            asm volatile("" ::: "memory");

            if (q == t) {                    // 16 lanes stage their point's h
                unsigned* hp = hs + m16 * 10;
                *(uint2*)&hp[0] = make_uint2(hd[0], hd[1]);
                *(uint2*)&hp[2] = make_uint2(hd[2], hd[3]);
                *(uint2*)&hp[4] = make_uint2(hd[4], hd[5]);
                *(uint2*)&hp[6] = make_uint2(hd[6], hd[7]);
            }
            half4 b1 = as_h4(*(const uint2*)&hs[m16 * 10 + 2 * q]);

            // L1: 16->64, relu; output rows permuted per grow()
            uint2 b2u[4];
            #pragma unroll
            for (int mo = 0; mo < 4; ++mo) {
                floatx4 c = MFMA16(A1[mo], b1, cz);
                b2u[mo] = make_uint2(pkrelu(c[0], c[1]), pkrelu(c[2], c[3]));
            }
            // L2: 64->16 linear, native K=32 (B-frag = concat of chunk pairs)
            half8 bk20 = as_h8(make_uint4(b2u[0].x, b2u[0].y, b2u[1].x, b2u[1].y));
            half8 bk21 = as_h8(make_uint4(b2u[2].x, b2u[2].y, b2u[3].x, b2u[3].y));
            floatx4 c2 = MFMA32(A2[0], bk20, cz);
            c2 = MFMA32(A2[1], bk21, c2);
            half4 b3 = as_h4(make_uint2(pk2(c2[0], c2[1]), pk2(c2[2], c2[3])));

            // L3: 16->64, relu; rows permuted
            uint2 b4u[4];
            #pragma unroll
            for (int mo = 0; mo < 4; ++mo) {
                floatx4 c = MFMA16(A3[mo], b3, cz);
                b4u[mo] = make_uint2(pkrelu(c[0], c[1]), pkrelu(c[2], c[3]));
            }
            // L4: 64->64 relu + L5 dot(r3); native K=32, A4 streamed from LDS
            half8 bk40 = as_h8(make_uint4(b4u[0].x, b4u[0].y, b4u[1].x, b4u[1].y));
            half8 bk41 = as_h8(make_uint4(b4u[2].x, b4u[2].y, b4u[3].x, b4u[3].y));
            float z = 0.f;
            #pragma unroll
            for (int mo = 0; mo < 4; ++mo) {
                half8 a40 = as_h8(r2s4[(0 * 4 + mo) * 64 + lane]);
                half8 a41 = as_h8(r2s4[(1 * 4 + mo) * 64 + lane]);
                floatx4 c = MFMA32(a40, bk40, cz);
                c = MFMA32(a41, bk41, c);
                UH2 ra, rb; ra.u = r3p[mo * 2 + 0]; rb.u = r3p[mo * 2 + 1];
                z = fmaf(fmaxf(c[0], 0.f), (float)ra.f[0], z);
                z = fmaf(fmaxf(c[1], 0.f), (float)ra.f[1], z);
                z = fmaf(fmaxf(c[2], 0.f), (float)rb.f[0], z);
                z = fmaf(fmaxf(c[3], 0.f), (float)rb.f[1], z);
            }
            z += __shfl_xor(z, 16);
            z += __shfl_xor(z, 32);
            if (lane < 16)
                out[pbase + wv * 64 + t * 16 + lane] = 1.0f / (1.0f + __expf(-z));
        }
    }
}

extern "C" void kernel_launch(void* const* d_in, const int* in_sizes, int n_in,
                              void* d_out, int out_size, void* d_ws, size_t ws_size,
                              hipStream_t stream)
{
    const float* x  = (const float*)d_in[0];
    const float* tb = (const float*)d_in[1];
    const float* w1 = (const float*)d_in[2];
    const float* w2 = (const float*)d_in[3];
    const float* r1 = (const float*)d_in[4];
    const float* r2 = (const float*)d_in[5];
    const float* r3 = (const float*)d_in[6];
    float* out = (float*)d_out;
    const int N = in_sizes[0] / 3;

    // Replicate numpy: B_SCALE = exp(log(20*0.5/2)/(L-1)); RES = floor(2*B^l)
    Res8 res;
    double b = exp(log(20.0 * 0.5 / 2.0) / (double)(NLVL - 1));
    for (int l = 0; l < NLVL; ++l)
        res.r[l] = (float)floor(2.0 * pow(b, (double)l));

    // 1024 blocks x 512 thr x 4 iters == 2M exactly. 45KB LDS -> 3 blocks/CU.
    const int blocks = 1024, threads = 512;
    const int iters = N / (blocks * threads);
    ngp_mfma_kernel<<<blocks, threads, 0, stream>>>(x, tb, w1, w2, r1, r2, r3,
                                                    out, N, iters, res);
}

// Round 15
// 134.055 us; speedup vs baseline: 1.1533x; 1.0111x over previous
//
#include <hip/hip_runtime.h>
#include <math.h>

#define NLVL 8
#define PR1 2654435761u
#define PR2 805459861u

typedef __fp16    f16x2 __attribute__((ext_vector_type(2)));   // cvt_pkrtz return type
typedef _Float16  half4 __attribute__((ext_vector_type(4)));   // 16x16x16 MFMA operand
typedef _Float16  half8 __attribute__((ext_vector_type(8)));   // 16x16x32 MFMA operand
typedef float     floatx4 __attribute__((ext_vector_type(4)));

#define MFMA16(a,b,c) __builtin_amdgcn_mfma_f32_16x16x16f16(a,b,c,0,0,0)
#define MFMA32(a,b,c) __builtin_amdgcn_mfma_f32_16x16x32_f16(a,b,c,0,0,0)

union UH2 { unsigned u; f16x2 f; };

struct Res8 { float r[NLVL]; };

__device__ __forceinline__ unsigned pk2(float a, float b) {
    UH2 c; c.f = __builtin_amdgcn_cvt_pkrtz(a, b); return c.u;
}
__device__ __forceinline__ unsigned pkrelu(float a, float b) {
    UH2 c; c.f = __builtin_amdgcn_cvt_pkrtz(a, b);
    f16x2 z = {(__fp16)0.f, (__fp16)0.f};
    c.f = __builtin_elementwise_max(c.f, z);                   // v_pk_max_f16
    return c.u;
}
__device__ __forceinline__ half4 as_h4(uint2 u) {
    union { uint2 u; half4 h; } c; c.u = u; return c.h;
}
__device__ __forceinline__ half8 as_h8(uint4 u) {
    union { uint4 u; half8 h; } c; c.u = u; return c.h;
}
__device__ __forceinline__ f16x2 lerp2(f16x2 a, f16x2 b, f16x2 t) {
    return a + t * (b - a);                                    // v_pk_sub + v_pk_fma
}
// Row permutation enabling K=32 consumption of K=16 chunk outputs:
// chunk mo (=2*kc+b), local row m (=4*qm+r) -> global row 32*kc + 8*qm + 4*b + r.
__device__ __forceinline__ int grow(int mo, int m) {
    return 32 * (mo >> 1) + (m >> 2) * 8 + 4 * (mo & 1) + (m & 3);
}

// Fused NGP: LDS hash-grid encode + register-resident MFMA MLP.
// r15 issue-slot cuts (issue ports ~93% saturated at r14):
//  - hash muls in fp32: only low-10 product bits survive the mask, so
//    multiply by (PRIME&1023)*4 = 1732/2132 exactly in f32 (range < 2^24),
//    replacing quarter-rate v_mul_lo_u32.
//  - staging once per tile-PAIR via 2 ds_write_b128 (slot stride 12 dw,
//    16B-aligned): 16 -> 4 ds_write per task.
//  - packed f16 relu-dot epilogue (pk_fma), f16 accum (|terms| ~1e-5 vs 1e-2 tol).
//  - tile loop unrolled 2 (VGPR headroom: r14 was 40/64).
__global__ __launch_bounds__(512, 4)
void ngp_mfma_kernel(const float* __restrict__ x,
                     const float* __restrict__ table,
                     const float* __restrict__ w1,
                     const float* __restrict__ w2,
                     const float* __restrict__ r1,
                     const float* __restrict__ r2,
                     const float* __restrict__ r3,
                     float* __restrict__ out,
                     int N, int iters, Res8 res)
{
    __shared__ unsigned tab[NLVL * 1024];            // 32 KB packed f16x2
    __shared__ __align__(16) unsigned hstg[8][384];  // 12 KB: 32 pts x 12 dw/wave
    __shared__ uint4    r2s4[512];                   // 8 KB: r2 as K32 A-frags

    const int tid  = threadIdx.x;
    const int lane = tid & 63, wv = tid >> 6;
    const int m16  = lane & 15, q = lane >> 4;

    {   // stage table: 8192 float2 -> 8192 packed dwords
        const float2* src = (const float2*)table;
        #pragma unroll
        for (int k = 0; k < 16; ++k) {
            int i = tid + 512 * k;
            float2 v = src[i];
            tab[i] = pk2(v.x, v.y);
        }
    }
    {   // stage r2 as natural K32 A-frags: fid = kc*4+mo, one uint4 per lane
        int fid = tid >> 6, ln = tid & 63;
        int kc = fid >> 2, mo = fid & 3;
        int m = ln & 15, qq = ln >> 4;
        const float* rr = r2 + (kc * 32 + qq * 8) * 64 + mo * 16 + m;
        r2s4[tid] = make_uint4(pk2(rr[0],   rr[64]),  pk2(rr[128], rr[192]),
                               pk2(rr[256], rr[320]), pk2(rr[384], rr[448]));
    }

    // Persistent frags: A1,A3 (8+8 regs, permuted rows), A2 K32 (8), r3 (8).
    half4 A1[4], A3[4];
    half8 A2[2];
    #pragma unroll
    for (int mo = 0; mo < 4; ++mo) {
        int g = grow(mo, m16);
        #pragma unroll
        for (int j = 0; j < 4; ++j) {
            int k = q * 4 + j;
            A1[mo][j] = (_Float16)w1[k * 64 + g];
            A3[mo][j] = (_Float16)r1[k * 64 + g];
        }
    }
    #pragma unroll
    for (int kc = 0; kc < 2; ++kc)
        #pragma unroll
        for (int j = 0; j < 8; ++j)
            A2[kc][j] = (_Float16)w2[(kc * 32 + q * 8 + j) * 16 + m16];
    unsigned r3p[8];
    #pragma unroll
    for (int mo = 0; mo < 4; ++mo) {
        r3p[mo * 2 + 0] = pk2(r3[mo * 16 + q * 4 + 0], r3[mo * 16 + q * 4 + 1]);
        r3p[mo * 2 + 1] = pk2(r3[mo * 16 + q * 4 + 2], r3[mo * 16 + q * 4 + 3]);
    }

    __syncthreads();                        // table+r2s visible; only barrier

    unsigned* hs = hstg[wv];
    const char* tabb = (const char*)tab;
    const floatx4 cz = {0.f, 0.f, 0.f, 0.f};

    #pragma unroll 1
    for (int it = 0; it < iters; ++it) {
        const int pbase = (it * (int)gridDim.x + (int)blockIdx.x) * 512;
        int p = pbase + tid;                 // grid*threads*iters == N exactly

        float px = x[3 * p + 0] + 0.5f;
        float py = x[3 * p + 1] + 0.5f;
        float pz = x[3 * p + 2] + 0.5f;

        // ---- encode: 8 levels, 7-lerp trilinear tree; hd stays in regs ----
        unsigned hd[8];
        #pragma unroll
        for (int l = 0; l < NLVL; ++l) {
            const float rf = res.r[l];
            float fx = px * rf, fy = py * rf, fz = pz * rf;
            float bx = floorf(fx), by = floorf(fy), bz = floorf(fz);
            UH2 wxp, wyp, wzp;
            wxp.f = __builtin_amdgcn_cvt_pkrtz(fx - bx, fx - bx);
            wyp.f = __builtin_amdgcn_cvt_pkrtz(fy - by, fy - by);
            wzp.f = __builtin_amdgcn_cvt_pkrtz(fz - bz, fz - bz);
            // Hash in BYTE offsets. Only low-10 bits of iy*PR1 survive the
            // mask, and (a*b) mod 1024 == (a * (b mod 1024)) mod 1024, so
            // multiply by (PR&1023)*4 in exact fp32 (by,bz <= 20 -> products
            // < 2^24): full-rate v_mul/v_fma + cvt vs quarter-rate v_mul_lo.
            unsigned ix = (unsigned)bx;
            unsigned x0 = (ix << 2) & 4092u,  x1 = (x0 + 4u) & 4092u;
            unsigned y0 = (unsigned)(by * 1732.0f) & 4092u;          // 433*4
            unsigned y1 = (unsigned)fmaf(by, 1732.0f, 1732.0f) & 4092u;
            unsigned z0 = (unsigned)(bz * 2132.0f) & 4092u;          // 533*4
            unsigned z1 = (unsigned)fmaf(bz, 2132.0f, 2132.0f) & 4092u;
            unsigned a00 = x0 ^ y0, a01 = x0 ^ y1, a10 = x1 ^ y0, a11 = x1 ^ y1;
            const char* tlb = tabb + (l << 12);
            UH2 c000, c001, c010, c011, c100, c101, c110, c111;
            c000.u = *(const unsigned*)(tlb + (a00 ^ z0));
            c001.u = *(const unsigned*)(tlb + (a00 ^ z1));
            c010.u = *(const unsigned*)(tlb + (a01 ^ z0));
            c011.u = *(const unsigned*)(tlb + (a01 ^ z1));
            c100.u = *(const unsigned*)(tlb + (a10 ^ z0));
            c101.u = *(const unsigned*)(tlb + (a10 ^ z1));
            c110.u = *(const unsigned*)(tlb + (a11 ^ z0));
            c111.u = *(const unsigned*)(tlb + (a11 ^ z1));
            f16x2 zz00 = lerp2(c000.f, c001.f, wzp.f);
            f16x2 zz01 = lerp2(c010.f, c011.f, wzp.f);
            f16x2 zz10 = lerp2(c100.f, c101.f, wzp.f);
            f16x2 zz11 = lerp2(c110.f, c111.f, wzp.f);
            f16x2 yy0  = lerp2(zz00, zz01, wyp.f);
            f16x2 yy1  = lerp2(zz10, zz11, wyp.f);
            UH2 r; r.f = lerp2(yy0, yy1, wxp.f);
            hd[l] = r.u;                     // packed features (2l, 2l+1)
        }

        // ---- MLP: 4 tiles of 16 points, processed in pairs ----
        #pragma unroll 1
        for (int tp = 0; tp < 2; ++tp) {
            // keep per-tile r2s frag loads inside the loop (LICM -> spills)
            asm volatile("" ::: "memory");

            // lanes q in {2tp, 2tp+1} stage BOTH tiles of this pair:
            // slot = (q&1)*16 + m16, stride 12 dw (48B -> b128-aligned)
            if ((q >> 1) == tp) {
                unsigned* hp = hs + ((q & 1) * 16 + m16) * 12;
                *(uint4*)&hp[0] = make_uint4(hd[0], hd[1], hd[2], hd[3]);
                *(uint4*)&hp[4] = make_uint4(hd[4], hd[5], hd[6], hd[7]);
            }

            #pragma unroll
            for (int ts = 0; ts < 2; ++ts) {
                const int t = tp * 2 + ts;
                half4 b1 = as_h4(*(const uint2*)&hs[(ts * 16 + m16) * 12 + 2 * q]);

                // L1: 16->64, relu; output rows permuted per grow()
                uint2 b2u[4];
                #pragma unroll
                for (int mo = 0; mo < 4; ++mo) {
                    floatx4 c = MFMA16(A1[mo], b1, cz);
                    b2u[mo] = make_uint2(pkrelu(c[0], c[1]), pkrelu(c[2], c[3]));
                }
                // L2: 64->16 linear, native K=32
                half8 bk20 = as_h8(make_uint4(b2u[0].x, b2u[0].y, b2u[1].x, b2u[1].y));
                half8 bk21 = as_h8(make_uint4(b2u[2].x, b2u[2].y, b2u[3].x, b2u[3].y));
                floatx4 c2 = MFMA32(A2[0], bk20, cz);
                c2 = MFMA32(A2[1], bk21, c2);
                half4 b3 = as_h4(make_uint2(pk2(c2[0], c2[1]), pk2(c2[2], c2[3])));

                // L3: 16->64, relu; rows permuted
                uint2 b4u[4];
                #pragma unroll
                for (int mo = 0; mo < 4; ++mo) {
                    floatx4 c = MFMA16(A3[mo], b3, cz);
                    b4u[mo] = make_uint2(pkrelu(c[0], c[1]), pkrelu(c[2], c[3]));
                }
                // L4: 64->64 relu + L5 dot(r3), packed f16 accumulation
                half8 bk40 = as_h8(make_uint4(b4u[0].x, b4u[0].y, b4u[1].x, b4u[1].y));
                half8 bk41 = as_h8(make_uint4(b4u[2].x, b4u[2].y, b4u[3].x, b4u[3].y));
                f16x2 zacc = {(__fp16)0.f, (__fp16)0.f};
                #pragma unroll
                for (int mo = 0; mo < 4; ++mo) {
                    half8 a40 = as_h8(r2s4[(0 * 4 + mo) * 64 + lane]);
                    half8 a41 = as_h8(r2s4[(1 * 4 + mo) * 64 + lane]);
                    floatx4 c = MFMA32(a40, bk40, cz);
                    c = MFMA32(a41, bk41, c);
                    UH2 p01, p23, ra, rb;
                    p01.u = pkrelu(c[0], c[1]);
                    p23.u = pkrelu(c[2], c[3]);
                    ra.u = r3p[mo * 2 + 0]; rb.u = r3p[mo * 2 + 1];
                    zacc = zacc + p01.f * ra.f;     // v_pk_fma_f16
                    zacc = zacc + p23.f * rb.f;
                }
                float z = (float)zacc[0] + (float)zacc[1];
                z += __shfl_xor(z, 16);
                z += __shfl_xor(z, 32);
                if (lane < 16)
                    out[pbase + wv * 64 + t * 16 + lane] = 1.0f / (1.0f + __expf(-z));
            }
        }
    }
}

extern "C" void kernel_launch(void* const* d_in, const int* in_sizes, int n_in,
                              void* d_out, int out_size, void* d_ws, size_t ws_size,
                              hipStream_t stream)
{
    const float* x  = (const float*)d_in[0];
    const float* tb = (const float*)d_in[1];
    const float* w1 = (const float*)d_in[2];
    const float* w2 = (const float*)d_in[3];
    const float* r1 = (const float*)d_in[4];
    const float* r2 = (const float*)d_in[5];
    const float* r3 = (const float*)d_in[6];
    float* out = (float*)d_out;
    const int N = in_sizes[0] / 3;

    // Replicate numpy: B_SCALE = exp(log(20*0.5/2)/(L-1)); RES = floor(2*B^l)
    Res8 res;
    double b = exp(log(20.0 * 0.5 / 2.0) / (double)(NLVL - 1));
    for (int l = 0; l < NLVL; ++l)
        res.r[l] = (float)floor(2.0 * pow(b, (double)l));

    // 1024 blocks x 512 thr x 4 iters == 2M exactly. 52KB LDS -> 3 blocks/CU.
    const int blocks = 1024, threads = 512;
    const int iters = N / (blocks * threads);
    ngp_mfma_kernel<<<blocks, threads, 0, stream>>>(x, tb, w1, w2, r1, r2, r3,
                                                    out, N, iters, res);
}